// Round 1
// baseline (160.169 us; speedup 1.0000x reference)
//
#include <hip/hip_runtime.h>

// Noise_Cell: out[i] = G[idx[i]] * (1 + 0.03 * eps[i])
// G: 8-entry f32 LUT; eps: f32 [64,1024,1024]; idx: i32 in [0,8).
// Memory-bound: 805 MB/launch -> ~128 us at 6.3 TB/s.

constexpr int CLEVEL = 8;
constexpr float NOISE_PARAM = 0.03f;

__global__ __launch_bounds__(256) void noise_cell_kernel(
    const float* __restrict__ G,
    const float* __restrict__ eps,
    const int*   __restrict__ idx,
    float*       __restrict__ out,
    long long n4)   // number of float4 elements
{
    __shared__ float sG[CLEVEL];
    if (threadIdx.x < CLEVEL) sG[threadIdx.x] = G[threadIdx.x];
    __syncthreads();

    long long tid    = (long long)blockIdx.x * blockDim.x + threadIdx.x;
    long long stride = (long long)gridDim.x * blockDim.x;

    const float4* __restrict__ e4 = (const float4*)eps;
    const int4*   __restrict__ i4 = (const int4*)idx;
    float4*       __restrict__ o4 = (float4*)out;

    for (long long i = tid; i < n4; i += stride) {
        float4 e = e4[i];
        int4   x = i4[i];
        float4 o;
        o.x = sG[x.x] * (1.0f + NOISE_PARAM * e.x);
        o.y = sG[x.y] * (1.0f + NOISE_PARAM * e.y);
        o.z = sG[x.z] * (1.0f + NOISE_PARAM * e.z);
        o.w = sG[x.w] * (1.0f + NOISE_PARAM * e.w);
        o4[i] = o;
    }
}

// Scalar tail kernel (not needed for 64*1024*1024, but keep it correct for
// any size): handles elements not covered by the vectorized kernel.
__global__ void noise_cell_tail(
    const float* __restrict__ G,
    const float* __restrict__ eps,
    const int*   __restrict__ idx,
    float*       __restrict__ out,
    long long start, long long n)
{
    __shared__ float sG[CLEVEL];
    if (threadIdx.x < CLEVEL) sG[threadIdx.x] = G[threadIdx.x];
    __syncthreads();
    long long i = start + blockIdx.x * (long long)blockDim.x + threadIdx.x;
    if (i < n) {
        out[i] = sG[idx[i]] * (1.0f + NOISE_PARAM * eps[i]);
    }
}

extern "C" void kernel_launch(void* const* d_in, const int* in_sizes, int n_in,
                              void* d_out, int out_size, void* d_ws, size_t ws_size,
                              hipStream_t stream) {
    // setup_inputs() dict order: G (8 f32), eps (f32), idx (i32)
    const float* G   = (const float*)d_in[0];
    const float* eps = (const float*)d_in[1];
    const int*   idx = (const int*)d_in[2];
    float*       out = (float*)d_out;

    long long n  = (long long)in_sizes[1];   // 64*1024*1024 = 67108864
    long long n4 = n / 4;                    // 16777216 float4s

    const int block = 256;
    int grid = 2048;                          // 256 CUs x 8 blocks, grid-stride
    long long needed = (n4 + block - 1) / block;
    if (needed < grid) grid = (int)needed;
    if (grid < 1) grid = 1;

    noise_cell_kernel<<<grid, block, 0, stream>>>(G, eps, idx, out, n4);

    long long rem = n - n4 * 4;
    if (rem > 0) {
        int tgrid = (int)((rem + block - 1) / block);
        noise_cell_tail<<<tgrid, block, 0, stream>>>(G, eps, idx, out, n4 * 4, n);
    }
}

// Round 3
// 143.206 us; speedup vs baseline: 1.1185x; 1.1185x over previous
//
#include <hip/hip_runtime.h>

// Noise_Cell: out[i] = G[idx[i]] * (1 + 0.03 * eps[i])
// G: 8-entry f32 LUT; eps: f32 [64,1024,1024]; idx: i32 in [0,8).
// Memory-bound streaming. R1 was latency-bound (VGPR=8, no unroll, LDS
// gather dependency). R2: register-select LUT + unroll x4 + nt stores.
// R3: native ext_vector types (HIP_vector_type rejected by
// __builtin_nontemporal_store).

typedef float f32x4 __attribute__((ext_vector_type(4)));
typedef int   i32x4 __attribute__((ext_vector_type(4)));

constexpr float NOISE_PARAM = 0.03f;
constexpr int BLOCK  = 256;
constexpr int UNROLL = 4;   // float4s per thread

// 3-bit select from 8 uniform (SGPR-resident) values: 7 v_cndmask.
__device__ __forceinline__ float sel8(int x,
    float g0, float g1, float g2, float g3,
    float g4, float g5, float g6, float g7)
{
    float a  = (x & 1) ? g1 : g0;
    float b  = (x & 1) ? g3 : g2;
    float c  = (x & 1) ? g5 : g4;
    float d  = (x & 1) ? g7 : g6;
    float ab = (x & 2) ? b : a;
    float cd = (x & 2) ? d : c;
    return     (x & 4) ? cd : ab;
}

__global__ __launch_bounds__(BLOCK) void noise_cell_kernel(
    const float* __restrict__ G,
    const f32x4* __restrict__ e4,
    const i32x4* __restrict__ i4,
    f32x4*       __restrict__ o4,
    long long n4)   // number of float4 elements
{
    // Uniform loads -> s_load into SGPRs.
    const float g0 = G[0], g1 = G[1], g2 = G[2], g3 = G[3];
    const float g4 = G[4], g5 = G[5], g6 = G[6], g7 = G[7];

    long long base = (long long)blockIdx.x * (BLOCK * UNROLL) + threadIdx.x;

    if (base + (UNROLL - 1) * BLOCK < n4) {
        // Fast path: full tile. Issue all 8 loads before any use.
        f32x4 e[UNROLL];
        i32x4 x[UNROLL];
#pragma unroll
        for (int u = 0; u < UNROLL; ++u) e[u] = e4[base + (long long)u * BLOCK];
#pragma unroll
        for (int u = 0; u < UNROLL; ++u) x[u] = i4[base + (long long)u * BLOCK];
#pragma unroll
        for (int u = 0; u < UNROLL; ++u) {
            f32x4 o;
            o.x = sel8(x[u].x, g0,g1,g2,g3,g4,g5,g6,g7) * (1.0f + NOISE_PARAM * e[u].x);
            o.y = sel8(x[u].y, g0,g1,g2,g3,g4,g5,g6,g7) * (1.0f + NOISE_PARAM * e[u].y);
            o.z = sel8(x[u].z, g0,g1,g2,g3,g4,g5,g6,g7) * (1.0f + NOISE_PARAM * e[u].z);
            o.w = sel8(x[u].w, g0,g1,g2,g3,g4,g5,g6,g7) * (1.0f + NOISE_PARAM * e[u].w);
            __builtin_nontemporal_store(o, &o4[base + (long long)u * BLOCK]);
        }
    } else {
        // Edge tile: per-access guard.
#pragma unroll
        for (int u = 0; u < UNROLL; ++u) {
            long long i = base + (long long)u * BLOCK;
            if (i < n4) {
                f32x4 e = e4[i];
                i32x4 x = i4[i];
                f32x4 o;
                o.x = sel8(x.x, g0,g1,g2,g3,g4,g5,g6,g7) * (1.0f + NOISE_PARAM * e.x);
                o.y = sel8(x.y, g0,g1,g2,g3,g4,g5,g6,g7) * (1.0f + NOISE_PARAM * e.y);
                o.z = sel8(x.z, g0,g1,g2,g3,g4,g5,g6,g7) * (1.0f + NOISE_PARAM * e.z);
                o.w = sel8(x.w, g0,g1,g2,g3,g4,g5,g6,g7) * (1.0f + NOISE_PARAM * e.w);
                __builtin_nontemporal_store(o, &o4[i]);
            }
        }
    }
}

// Scalar tail for n % 4 remainder (none at 64*1024*1024, kept for generality).
__global__ void noise_cell_tail(
    const float* __restrict__ G,
    const float* __restrict__ eps,
    const int*   __restrict__ idx,
    float*       __restrict__ out,
    long long start, long long n)
{
    const float g0 = G[0], g1 = G[1], g2 = G[2], g3 = G[3];
    const float g4 = G[4], g5 = G[5], g6 = G[6], g7 = G[7];
    long long i = start + blockIdx.x * (long long)blockDim.x + threadIdx.x;
    if (i < n) {
        out[i] = sel8(idx[i], g0,g1,g2,g3,g4,g5,g6,g7)
                 * (1.0f + NOISE_PARAM * eps[i]);
    }
}

extern "C" void kernel_launch(void* const* d_in, const int* in_sizes, int n_in,
                              void* d_out, int out_size, void* d_ws, size_t ws_size,
                              hipStream_t stream) {
    // setup_inputs() dict order: G (8 f32), eps (f32), idx (i32)
    const float* G   = (const float*)d_in[0];
    const float* eps = (const float*)d_in[1];
    const int*   idx = (const int*)d_in[2];
    float*       out = (float*)d_out;

    long long n  = (long long)in_sizes[1];   // 67108864
    long long n4 = n / 4;                    // 16777216

    long long per_block = (long long)BLOCK * UNROLL;          // 1024 float4s
    int grid = (int)((n4 + per_block - 1) / per_block);       // 16384
    if (grid > 0) {
        noise_cell_kernel<<<grid, BLOCK, 0, stream>>>(
            G, (const f32x4*)eps, (const i32x4*)idx, (f32x4*)out, n4);
    }

    long long rem = n - n4 * 4;
    if (rem > 0) {
        int tgrid = (int)((rem + BLOCK - 1) / BLOCK);
        noise_cell_tail<<<tgrid, BLOCK, 0, stream>>>(G, eps, idx, out, n4 * 4, n);
    }
}